// Round 2
// baseline (267.058 us; speedup 1.0000x reference)
//
#include <hip/hip_runtime.h>
#include <hip/hip_bf16.h>
#include <math.h>

#define ALPHA 0.2f
#define LOG2E 1.4426950408889634f

constexpr int B_ = 4, N_ = 2048, F_ = 256, T_ = 8, H_ = 4, D_ = 64;
constexpr int FT = F_ + T_; // 264

using short8  = __attribute__((ext_vector_type(8))) short;
using float4v = __attribute__((ext_vector_type(4))) float;
using uint4v  = __attribute__((ext_vector_type(4))) unsigned;

#if __has_builtin(__builtin_amdgcn_exp2f)
#define EXP2F(x) __builtin_amdgcn_exp2f(x)
#else
#define EXP2F(x) exp2f(x)
#endif

// ---- workspace byte offsets (all 16B aligned) ----
#define V1_OFF   0u            // 4*264 f32
#define V2_OFF   4224u         // 4*264 f32
#define E1_OFF   8448u         // 4*4*2048 f32 (pre-scaled by log2e)
#define E2_OFF   139520u       // 4*4*2048 f32
#define S_OFF    270592u       // 4*4*2048 f32 : column sums (atomic)
#define C_OFF    401664u       // 4*4*2048 f32 : 1/s per column
#define WT_OFF   532736u       // 256*256 bf16 : W transposed [hd][f]
#define BITS_OFF 663808u       // 4*2048*64 u32 : adj bitmask (2 MB)
#define WHT_OFF  2760960u      // 4*256*2048 bf16 : Wh transposed [b][hd][j]
// end: 6955264 bytes

__device__ inline unsigned short f2bf_rne(float f) {
    unsigned u = __builtin_bit_cast(unsigned, f);
    u += 0x7FFFu + ((u >> 16) & 1u);
    return (unsigned short)(u >> 16);
}
__device__ inline unsigned pack_bf_rne(float f0, float f1) {
    return (unsigned)f2bf_rne(f0) | ((unsigned)f2bf_rne(f1) << 16);
}
__device__ inline unsigned pack_bf_trunc(float f0, float f1) {
    unsigned u0 = __builtin_bit_cast(unsigned, f0);
    unsigned u1 = __builtin_bit_cast(unsigned, f1);
    return (u0 >> 16) | (u1 & 0xFFFF0000u);
}

// K0: adj (int32 0/1, 64 MB) -> bitmask (2 MB). Coalesced read, ballot pack.
__global__ __launch_bounds__(256) void k_adjpack(const int* __restrict__ adj,
                                                 unsigned* __restrict__ bits) {
    size_t tid = (size_t)blockIdx.x * 256 + threadIdx.x;  // 16,777,216 total
    int av = adj[tid];
    unsigned long long msk = __ballot(av != 0);
    int lane = threadIdx.x & 63;
    if (lane == 0)       bits[tid >> 5] = (unsigned)msk;
    else if (lane == 32) bits[tid >> 5] = (unsigned)(msk >> 32);
}

// K1: v1[h,f] = log2e * sum_d Wq[h,f,d]*a[h,d] ; v2 from Wk with a[h,64+d]
__global__ __launch_bounds__(256) void k_prep_v(const float* __restrict__ Wq,
                                                const float* __restrict__ Wk,
                                                const float* __restrict__ a,
                                                float* __restrict__ v1,
                                                float* __restrict__ v2) {
    int tid = blockIdx.x * 256 + threadIdx.x;
    if (tid >= 2 * H_ * FT) return;
    int sel = tid / (H_ * FT);
    int r = tid - sel * (H_ * FT);
    int h = r / FT, f = r - h * FT;
    const float* W = sel ? Wk : Wq;
    const float* av = a + h * 2 * D_ + sel * D_;
    const float* wrow = W + (size_t)(h * FT + f) * D_;
    float acc = 0.f;
    for (int d = 0; d < D_; ++d) acc += wrow[d] * av[d];
    (sel ? v2 : v1)[h * FT + f] = acc * LOG2E;
}

// K1b: WT[hd][f] = bf16(W[h][f][d])
__global__ __launch_bounds__(256) void k_prep_wt(const float* __restrict__ W,
                                                 unsigned short* __restrict__ WT) {
    int tid = blockIdx.x * 256 + threadIdx.x;  // 65536 total
    int hd = tid >> 8, f = tid & 255;
    int h = hd >> 6, d = hd & 63;
    WT[(size_t)hd * F_ + f] = f2bf_rne(W[((size_t)h * F_ + f) * D_ + d]);
}

// K2: e1'[b,h,n], e2'[b,h,n] — one wave per (b,n)
__global__ __launch_bounds__(256) void k_e12(const float* __restrict__ x,
                                             const float* __restrict__ oh,
                                             const float* __restrict__ v1,
                                             const float* __restrict__ v2,
                                             float* __restrict__ e1,
                                             float* __restrict__ e2) {
    int lane = threadIdx.x & 63;
    int w = threadIdx.x >> 6;
    int bn = blockIdx.x * 4 + w;
    int b = bn >> 11, n = bn & (N_ - 1);
    float a1h[H_] = {0.f, 0.f, 0.f, 0.f};
    float a2h[H_] = {0.f, 0.f, 0.f, 0.f};
    const float* xrow = x + (size_t)(b * N_ + n) * F_;
    for (int c = 0; c < 4; ++c) {
        int f = c * 64 + lane;
        float xv = xrow[f];
        #pragma unroll
        for (int h = 0; h < H_; ++h) {
            a1h[h] += xv * v1[h * FT + f];
            a2h[h] += xv * v2[h * FT + f];
        }
    }
    if (lane < T_) {
        float ov = oh[(size_t)(b * N_ + n) * T_ + lane];
        #pragma unroll
        for (int h = 0; h < H_; ++h) {
            a1h[h] += ov * v1[h * FT + F_ + lane];
            a2h[h] += ov * v2[h * FT + F_ + lane];
        }
    }
    #pragma unroll
    for (int off = 32; off; off >>= 1) {
        #pragma unroll
        for (int h = 0; h < H_; ++h) {
            a1h[h] += __shfl_xor(a1h[h], off, 64);
            a2h[h] += __shfl_xor(a2h[h], off, 64);
        }
    }
    if (lane == 0) {
        #pragma unroll
        for (int h = 0; h < H_; ++h) {
            e1[(size_t)(b * H_ + h) * N_ + n] = a1h[h];
            e2[(size_t)(b * H_ + h) * N_ + n] = a2h[h];
        }
    }
}

// K3: WhT[b][hd][j] = bf16( sum_f x[b,j,f] * W[h,f,d] )  via MFMA
__global__ __launch_bounds__(256) void k_wht(const float* __restrict__ x,
                                             const unsigned short* __restrict__ WT,
                                             unsigned short* __restrict__ WhT) {
    int lane = threadIdx.x;       // 64
    int h = threadIdx.y;          // 4
    int jt = blockIdx.x;          // 128
    int b  = blockIdx.y;          // 4
    int j0 = jt * 16;
    int m = lane & 15, quad = lane >> 4;
    float4v zero = {0.f, 0.f, 0.f, 0.f};
    float4v acc[4] = {zero, zero, zero, zero};
    for (int f0 = 0; f0 < F_; f0 += 32) {
        const float* xp = x + (size_t)(b * N_ + j0 + m) * F_ + f0 + quad * 8;
        float4v xlo = *(const float4v*)xp;
        float4v xhi = *(const float4v*)(xp + 4);
        uint4v bp = {pack_bf_rne(xlo[0], xlo[1]), pack_bf_rne(xlo[2], xlo[3]),
                     pack_bf_rne(xhi[0], xhi[1]), pack_bf_rne(xhi[2], xhi[3])};
        short8 bfrag = __builtin_bit_cast(short8, bp);
        #pragma unroll
        for (int mt = 0; mt < 4; ++mt) {
            const unsigned short* ap =
                WT + (size_t)(h * 64 + mt * 16 + m) * F_ + f0 + quad * 8;
            short8 afrag = *(const short8*)ap;
            acc[mt] = __builtin_amdgcn_mfma_f32_16x16x32_bf16(afrag, bfrag, acc[mt], 0, 0, 0);
        }
    }
    #pragma unroll
    for (int mt = 0; mt < 4; ++mt) {
        #pragma unroll
        for (int reg = 0; reg < 4; ++reg) {
            int hd = h * 64 + mt * 16 + quad * 4 + reg;
            WhT[((size_t)b * 256 + hd) * N_ + j0 + m] = f2bf_rne(acc[mt][reg]);
        }
    }
}

// K4: column sums s[b,h,j] via bitmask + atomic accumulation (s pre-zeroed)
__global__ __launch_bounds__(256) void k_colsum(const unsigned* __restrict__ bits,
                                                const float* __restrict__ e1,
                                                const float* __restrict__ e2,
                                                float* __restrict__ s) {
    int tid = threadIdx.x;   // 256
    int jt = blockIdx.x;     // 8
    int b  = blockIdx.y;     // 4
    int ic = blockIdx.z;     // 32 chunks of 64 rows
    int j = jt * 256 + tid;
    const float* e1b = e1 + (size_t)(b * H_) * N_;
    float e2h[H_], acc[H_] = {0.f, 0.f, 0.f, 0.f};
    #pragma unroll
    for (int h = 0; h < H_; ++h) e2h[h] = e2[(size_t)(b * H_ + h) * N_ + j];
    int i0 = ic * 64;
    const unsigned* bp = bits + ((size_t)b * N_ + i0) * 64 + (j >> 5);
    unsigned jbit = 1u << (j & 31);
    #pragma unroll 4
    for (int i = i0; i < i0 + 64; ++i) {
        unsigned wv = *bp;
        bp += 64;
        #pragma unroll
        for (int h = 0; h < H_; ++h) {
            float z = e1b[h * N_ + i] + e2h[h];
            float t = EXP2F(fmaxf(z, ALPHA * z));
            acc[h] += (wv & jbit) ? t : 0.f;
        }
    }
    #pragma unroll
    for (int h = 0; h < H_; ++h)
        atomicAdd(&s[(size_t)(b * H_ + h) * N_ + j], acc[h]);
}

// K4b: c = s>0 ? 1/s : 0
__global__ __launch_bounds__(256) void k_recip(const float* __restrict__ s,
                                               float* __restrict__ c) {
    int tid = blockIdx.x * 256 + threadIdx.x;  // 32768
    float v = s[tid];
    c[tid] = (v > 0.f) ? 1.f / v : 0.f;
}

// K6: h_prime partials — grid (it,b,jc): 16 i-rows × 512-wide j-chunk × all h.
// att rebuilt in-register (bitmask) as bf16 A-frags; atomicAdd into out (pre-zeroed).
__global__ __launch_bounds__(256) void k_main(const unsigned* __restrict__ bits,
                                              const float* __restrict__ e1,
                                              const float* __restrict__ e2,
                                              const float* __restrict__ cinv,
                                              const unsigned short* __restrict__ WhT,
                                              float* __restrict__ out) {
    int lane = threadIdx.x;   // 64
    int h = threadIdx.y;      // 4
    int it = blockIdx.x;      // 128
    int b  = blockIdx.y;      // 4
    int jc = blockIdx.z;      // 4 chunks of 512 j
    int I0 = it * 16;
    int m = lane & 15, quad = lane >> 4;

    float e1v = e1[(size_t)(b * H_ + h) * N_ + I0 + m];
    const float* e2p = e2 + (size_t)(b * H_ + h) * N_;
    const float* cp  = cinv + (size_t)(b * H_ + h) * N_;
    const unsigned* brow = bits + ((size_t)b * N_ + I0 + m) * 64;
    const unsigned short* bbase = WhT + (size_t)(b * H_ + h) * 64 * N_;

    float4v zero = {0.f, 0.f, 0.f, 0.f};
    float4v acc[4] = {zero, zero, zero, zero};

    int j0 = jc * 512;
    for (int jb = j0; jb < j0 + 512; jb += 32) {
        unsigned wv = brow[jb >> 5];          // bits for cols jb..jb+31, row I0+m
        unsigned wq = wv >> (quad * 8);       // this quad's 8 bits
        int jq = jb + quad * 8;
        float4v ez0 = *(const float4v*)(e2p + jq);
        float4v ez1 = *(const float4v*)(e2p + jq + 4);
        float4v c0 = *(const float4v*)(cp + jq);
        float4v c1 = *(const float4v*)(cp + jq + 4);

        float w[8];
        #pragma unroll
        for (int t = 0; t < 4; ++t) {
            float z = e1v + ez0[t];
            float p = EXP2F(fmaxf(z, ALPHA * z));
            w[t] = (wq & (1u << t)) ? p * c0[t] : 0.f;
        }
        #pragma unroll
        for (int t = 0; t < 4; ++t) {
            float z = e1v + ez1[t];
            float p = EXP2F(fmaxf(z, ALPHA * z));
            w[4 + t] = (wq & (16u << t)) ? p * c1[t] : 0.f;
        }
        uint4v apk = {pack_bf_trunc(w[0], w[1]), pack_bf_trunc(w[2], w[3]),
                      pack_bf_trunc(w[4], w[5]), pack_bf_trunc(w[6], w[7])};
        short8 afrag = __builtin_bit_cast(short8, apk);

        #pragma unroll
        for (int dt = 0; dt < 4; ++dt) {
            const unsigned short* bp = bbase + (size_t)(dt * 16 + m) * N_ + jq;
            short8 bfrag = *(const short8*)bp;
            acc[dt] = __builtin_amdgcn_mfma_f32_16x16x32_bf16(afrag, bfrag, acc[dt], 0, 0, 0);
        }
    }

    #pragma unroll
    for (int dt = 0; dt < 4; ++dt) {
        #pragma unroll
        for (int reg = 0; reg < 4; ++reg) {
            int i = I0 + quad * 4 + reg;
            int d = dt * 16 + m;
            atomicAdd(&out[((size_t)b * N_ + i) * (H_ * D_) + h * D_ + d],
                      acc[dt][reg]);
        }
    }
}

// K7: in-place ELU on out
__global__ __launch_bounds__(256) void k_elu(float* __restrict__ out) {
    size_t t = (size_t)blockIdx.x * 256 + threadIdx.x;  // 524288 float4s
    float4v v = ((float4v*)out)[t];
    #pragma unroll
    for (int c = 0; c < 4; ++c) v[c] = v[c] > 0.f ? v[c] : expm1f(v[c]);
    ((float4v*)out)[t] = v;
}

extern "C" void kernel_launch(void* const* d_in, const int* in_sizes, int n_in,
                              void* d_out, int out_size, void* d_ws, size_t ws_size,
                              hipStream_t stream) {
    const float* x   = (const float*)d_in[0];
    const int*   adj = (const int*)d_in[1];
    const float* oh  = (const float*)d_in[2];
    const float* Wq  = (const float*)d_in[3];
    const float* Wk  = (const float*)d_in[4];
    const float* W   = (const float*)d_in[5];
    const float* a   = (const float*)d_in[6];
    float* out = (float*)d_out;
    char* ws = (char*)d_ws;

    float* v1   = (float*)(ws + V1_OFF);
    float* v2   = (float*)(ws + V2_OFF);
    float* e1   = (float*)(ws + E1_OFF);
    float* e2   = (float*)(ws + E2_OFF);
    float* s    = (float*)(ws + S_OFF);
    float* cin  = (float*)(ws + C_OFF);
    unsigned short* WT  = (unsigned short*)(ws + WT_OFF);
    unsigned*       bits = (unsigned*)(ws + BITS_OFF);
    unsigned short* WhT = (unsigned short*)(ws + WHT_OFF);

    hipMemsetAsync(s, 0, (size_t)B_ * H_ * N_ * sizeof(float), stream);
    hipMemsetAsync(out, 0, (size_t)out_size * sizeof(float), stream);

    k_adjpack<<<65536, 256, 0, stream>>>(adj, bits);
    k_prep_v<<<9, 256, 0, stream>>>(Wq, Wk, a, v1, v2);
    k_prep_wt<<<256, 256, 0, stream>>>(W, WT);
    k_e12<<<B_ * N_ / 4, 256, 0, stream>>>(x, oh, v1, v2, e1, e2);
    k_wht<<<dim3(128, 4), dim3(64, 4), 0, stream>>>(x, WT, WhT);
    k_colsum<<<dim3(8, 4, 32), 256, 0, stream>>>(bits, e1, e2, s);
    k_recip<<<128, 256, 0, stream>>>(s, cin);
    k_main<<<dim3(128, 4, 4), dim3(64, 4), 0, stream>>>(bits, e1, e2, cin, WhT, out);
    k_elu<<<2048, 256, 0, stream>>>(out);
}

// Round 3
// 264.146 us; speedup vs baseline: 1.0110x; 1.0110x over previous
//
#include <hip/hip_runtime.h>
#include <hip/hip_bf16.h>
#include <math.h>

#define ALPHA 0.2f
#define LOG2E 1.4426950408889634f

constexpr int B_ = 4, N_ = 2048, F_ = 256, T_ = 8, H_ = 4, D_ = 64;
constexpr int FT = F_ + T_; // 264

using short8  = __attribute__((ext_vector_type(8))) short;
using float4v = __attribute__((ext_vector_type(4))) float;
using uint4v  = __attribute__((ext_vector_type(4))) unsigned;

#if __has_builtin(__builtin_amdgcn_exp2f)
#define EXP2F(x) __builtin_amdgcn_exp2f(x)
#else
#define EXP2F(x) exp2f(x)
#endif

// ---- workspace byte offsets (all 64B aligned) ----
#define V1_OFF    0u           // 4*264 f32
#define V2_OFF    4224u        // 4*264 f32
#define E1_OFF    8448u        // 4*4*2048 f32 (pre-scaled by log2e)
#define E2_OFF    139520u      // 4*4*2048 f32
#define C_OFF     270592u      // 4*4*2048 f32 : 1/s per column
#define PARTS_OFF 401664u      // 16*4*4*2048 f32 partial column sums (2 MB)
#define WT_OFF    2498816u     // 256*256 bf16 : W transposed [hd][f]
#define BITS_OFF  2629888u     // 4*2048*64 u32 : adj bitmask (2 MB)
#define WHT_OFF   4727040u     // 4*256*2048 bf16 : Wh transposed [b][hd][j]
// end: 8921344 bytes (~8.5 MB)

__device__ inline unsigned short f2bf_rne(float f) {
    unsigned u = __builtin_bit_cast(unsigned, f);
    u += 0x7FFFu + ((u >> 16) & 1u);
    return (unsigned short)(u >> 16);
}
__device__ inline unsigned pack_bf_rne(float f0, float f1) {
    return (unsigned)f2bf_rne(f0) | ((unsigned)f2bf_rne(f1) << 16);
}
__device__ inline unsigned pack_bf_trunc(float f0, float f1) {
    unsigned u0 = __builtin_bit_cast(unsigned, f0);
    unsigned u1 = __builtin_bit_cast(unsigned, f1);
    return (u0 >> 16) | (u1 & 0xFFFF0000u);
}

// K1: v1[h,f] = log2e * sum_d Wq[h,f,d]*a[h,d] ; v2 from Wk with a[h,64+d]
__global__ __launch_bounds__(256) void k_prep_v(const float* __restrict__ Wq,
                                                const float* __restrict__ Wk,
                                                const float* __restrict__ a,
                                                float* __restrict__ v1,
                                                float* __restrict__ v2) {
    int tid = blockIdx.x * 256 + threadIdx.x;
    if (tid >= 2 * H_ * FT) return;
    int sel = tid / (H_ * FT);
    int r = tid - sel * (H_ * FT);
    int h = r / FT, f = r - h * FT;
    const float* W = sel ? Wk : Wq;
    const float* av = a + h * 2 * D_ + sel * D_;
    const float* wrow = W + (size_t)(h * FT + f) * D_;
    float acc = 0.f;
    for (int d = 0; d < D_; ++d) acc += wrow[d] * av[d];
    (sel ? v2 : v1)[h * FT + f] = acc * LOG2E;
}

// K1b: WT[hd][f] = bf16(W[h][f][d])
__global__ __launch_bounds__(256) void k_prep_wt(const float* __restrict__ W,
                                                 unsigned short* __restrict__ WT) {
    int tid = blockIdx.x * 256 + threadIdx.x;  // 65536 total
    int hd = tid >> 8, f = tid & 255;
    int h = hd >> 6, d = hd & 63;
    WT[(size_t)hd * F_ + f] = f2bf_rne(W[((size_t)h * F_ + f) * D_ + d]);
}

// K2: e1'[b,h,n], e2'[b,h,n] — one wave per (b,n)
__global__ __launch_bounds__(256) void k_e12(const float* __restrict__ x,
                                             const float* __restrict__ oh,
                                             const float* __restrict__ v1,
                                             const float* __restrict__ v2,
                                             float* __restrict__ e1,
                                             float* __restrict__ e2) {
    int lane = threadIdx.x & 63;
    int w = threadIdx.x >> 6;
    int bn = blockIdx.x * 4 + w;
    int b = bn >> 11, n = bn & (N_ - 1);
    float a1h[H_] = {0.f, 0.f, 0.f, 0.f};
    float a2h[H_] = {0.f, 0.f, 0.f, 0.f};
    const float* xrow = x + (size_t)(b * N_ + n) * F_;
    for (int c = 0; c < 4; ++c) {
        int f = c * 64 + lane;
        float xv = xrow[f];
        #pragma unroll
        for (int h = 0; h < H_; ++h) {
            a1h[h] += xv * v1[h * FT + f];
            a2h[h] += xv * v2[h * FT + f];
        }
    }
    if (lane < T_) {
        float ov = oh[(size_t)(b * N_ + n) * T_ + lane];
        #pragma unroll
        for (int h = 0; h < H_; ++h) {
            a1h[h] += ov * v1[h * FT + F_ + lane];
            a2h[h] += ov * v2[h * FT + F_ + lane];
        }
    }
    #pragma unroll
    for (int off = 32; off; off >>= 1) {
        #pragma unroll
        for (int h = 0; h < H_; ++h) {
            a1h[h] += __shfl_xor(a1h[h], off, 64);
            a2h[h] += __shfl_xor(a2h[h], off, 64);
        }
    }
    if (lane == 0) {
        #pragma unroll
        for (int h = 0; h < H_; ++h) {
            e1[(size_t)(b * H_ + h) * N_ + n] = a1h[h];
            e2[(size_t)(b * H_ + h) * N_ + n] = a2h[h];
        }
    }
}

// K3: WhT[b][hd][j] = bf16( sum_f x[b,j,f] * W[h,f,d] )  via MFMA
__global__ __launch_bounds__(256) void k_wht(const float* __restrict__ x,
                                             const unsigned short* __restrict__ WT,
                                             unsigned short* __restrict__ WhT) {
    int lane = threadIdx.x;       // 64
    int h = threadIdx.y;          // 4
    int jt = blockIdx.x;          // 128
    int b  = blockIdx.y;          // 4
    int j0 = jt * 16;
    int m = lane & 15, quad = lane >> 4;
    float4v zero = {0.f, 0.f, 0.f, 0.f};
    float4v acc[4] = {zero, zero, zero, zero};
    for (int f0 = 0; f0 < F_; f0 += 32) {
        const float* xp = x + (size_t)(b * N_ + j0 + m) * F_ + f0 + quad * 8;
        float4v xlo = *(const float4v*)xp;
        float4v xhi = *(const float4v*)(xp + 4);
        uint4v bp = {pack_bf_rne(xlo[0], xlo[1]), pack_bf_rne(xlo[2], xlo[3]),
                     pack_bf_rne(xhi[0], xhi[1]), pack_bf_rne(xhi[2], xhi[3])};
        short8 bfrag = __builtin_bit_cast(short8, bp);
        #pragma unroll
        for (int mt = 0; mt < 4; ++mt) {
            const unsigned short* ap =
                WT + (size_t)(h * 64 + mt * 16 + m) * F_ + f0 + quad * 8;
            short8 afrag = *(const short8*)ap;
            acc[mt] = __builtin_amdgcn_mfma_f32_16x16x32_bf16(afrag, bfrag, acc[mt], 0, 0, 0);
        }
    }
    #pragma unroll
    for (int mt = 0; mt < 4; ++mt) {
        #pragma unroll
        for (int reg = 0; reg < 4; ++reg) {
            int hd = h * 64 + mt * 16 + quad * 4 + reg;
            WhT[((size_t)b * 256 + hd) * N_ + j0 + m] = f2bf_rne(acc[mt][reg]);
        }
    }
}

// K4 (fused): reads raw adj coalesced ONCE; emits bitmask (ballot) AND partial
// column sums. grid (8 jt, 4 b, 16 ic of 128 i), block 256.
__global__ __launch_bounds__(256) void k_colsum(const int* __restrict__ adj,
                                                const float* __restrict__ e1,
                                                const float* __restrict__ e2,
                                                float* __restrict__ part_s,
                                                unsigned* __restrict__ bits) {
    int tid = threadIdx.x;
    int jt = blockIdx.x, b = blockIdx.y, ic = blockIdx.z;
    int j = jt * 256 + tid;
    int i0 = ic * 128;
    const float* e1b = e1 + (size_t)(b * H_) * N_;
    float e2h[H_], acc[H_] = {0.f, 0.f, 0.f, 0.f};
    #pragma unroll
    for (int h = 0; h < H_; ++h) e2h[h] = e2[(size_t)(b * H_ + h) * N_ + j];
    const int* ap = adj + ((size_t)(b * N_ + i0)) * N_ + j;
    int lane = tid & 63;
    #pragma unroll 4
    for (int k = 0; k < 128; ++k) {
        int i = i0 + k;
        int av = ap[(size_t)k * N_];
        unsigned long long mk = __ballot(av != 0);
        if ((tid & 31) == 0)
            bits[(size_t)(b * N_ + i) * 64 + (j >> 5)] =
                (lane == 0) ? (unsigned)mk : (unsigned)(mk >> 32);
        #pragma unroll
        for (int h = 0; h < H_; ++h) {
            float z = e1b[h * N_ + i] + e2h[h];
            float t = EXP2F(fmaxf(z, ALPHA * z));
            acc[h] += (av != 0) ? t : 0.f;
        }
    }
    #pragma unroll
    for (int h = 0; h < H_; ++h)
        part_s[(size_t)ic * (B_ * H_ * N_) + (size_t)(b * H_ + h) * N_ + j] = acc[h];
}

// K4b: c = s>0 ? 1/s : 0
__global__ __launch_bounds__(256) void k_recip(const float* __restrict__ part_s,
                                               float* __restrict__ c) {
    int tid = blockIdx.x * 256 + threadIdx.x;  // 32768
    float s = 0.f;
    #pragma unroll
    for (int ic = 0; ic < 16; ++ic) s += part_s[(size_t)ic * (B_ * H_ * N_) + tid];
    c[tid] = (s > 0.f) ? 1.f / s : 0.f;
}

// K6: block = (64,4) = 4 waves, each wave one 512-j chunk of the SAME (b,h,i-tile).
// e2/c staged in LDS; bits preloaded (16 words); B-frags double-buffered.
// Cross-wave LDS reduction + fused ELU; single non-atomic store of out.
__global__ __launch_bounds__(256, 4) void k_main(const unsigned* __restrict__ bits,
                                                 const float* __restrict__ e1,
                                                 const float* __restrict__ e2,
                                                 const float* __restrict__ cinv,
                                                 const unsigned short* __restrict__ WhT,
                                                 float* __restrict__ out) {
    __shared__ float smem[4096];  // phase1: e2[0..2047], c[2048..4095]; phase2: reduction
    int lane = threadIdx.x;   // 64
    int wy = threadIdx.y;     // 4 : j-chunk
    int it_ = blockIdx.x;     // 128
    int b  = blockIdx.y;      // 4
    int h  = blockIdx.z;      // 4
    int I0 = it_ * 16;
    int m = lane & 15, quad = lane >> 4;

    // stage e2/c for all 2048 j of (b,h)
    {
        const float* e2p = e2 + (size_t)(b * H_ + h) * N_;
        const float* cp  = cinv + (size_t)(b * H_ + h) * N_;
        int base = wy * 512 + lane * 8;
        *(float4v*)&smem[base]          = *(const float4v*)(e2p + base);
        *(float4v*)&smem[base + 4]      = *(const float4v*)(e2p + base + 4);
        *(float4v*)&smem[2048 + base]     = *(const float4v*)(cp + base);
        *(float4v*)&smem[2048 + base + 4] = *(const float4v*)(cp + base + 4);
    }
    float e1v = e1[(size_t)(b * H_ + h) * N_ + I0 + m];
    const unsigned short* bbase = WhT + (size_t)(b * 256 + h * 64) * N_;
    uint4v bw[4];
    {
        const unsigned* brow = bits + ((size_t)(b * N_) + I0 + m) * 64 + wy * 16;
        bw[0] = ((const uint4v*)brow)[0];
        bw[1] = ((const uint4v*)brow)[1];
        bw[2] = ((const uint4v*)brow)[2];
        bw[3] = ((const uint4v*)brow)[3];
    }
    __syncthreads();

    int j0 = wy * 512;
    float4v zero = {0.f, 0.f, 0.f, 0.f};
    float4v acc[4] = {zero, zero, zero, zero};

    short8 bf[2][4];
    {
        int jq = j0 + quad * 8;
        #pragma unroll
        for (int dt = 0; dt < 4; ++dt)
            bf[0][dt] = *(const short8*)(bbase + (size_t)(dt * 16 + m) * N_ + jq);
    }

    #pragma unroll
    for (int t = 0; t < 16; ++t) {
        int cb = t & 1;
        if (t < 15) {
            int jqn = j0 + (t + 1) * 32 + quad * 8;
            #pragma unroll
            for (int dt = 0; dt < 4; ++dt)
                bf[cb ^ 1][dt] = *(const short8*)(bbase + (size_t)(dt * 16 + m) * N_ + jqn);
        }
        unsigned word = bw[t >> 2][t & 3];
        unsigned wq = word >> (quad * 8);
        int jl = j0 + t * 32 + quad * 8;
        float4v ez0 = *(const float4v*)&smem[jl];
        float4v ez1 = *(const float4v*)&smem[jl + 4];
        float4v c0  = *(const float4v*)&smem[2048 + jl];
        float4v c1  = *(const float4v*)&smem[2048 + jl + 4];

        float w[8];
        #pragma unroll
        for (int t4 = 0; t4 < 4; ++t4) {
            float z = e1v + ez0[t4];
            float p = EXP2F(fmaxf(z, ALPHA * z));
            w[t4] = (wq & (1u << t4)) ? p * c0[t4] : 0.f;
        }
        #pragma unroll
        for (int t4 = 0; t4 < 4; ++t4) {
            float z = e1v + ez1[t4];
            float p = EXP2F(fmaxf(z, ALPHA * z));
            w[4 + t4] = (wq & (16u << t4)) ? p * c1[t4] : 0.f;
        }
        uint4v apk = {pack_bf_trunc(w[0], w[1]), pack_bf_trunc(w[2], w[3]),
                      pack_bf_trunc(w[4], w[5]), pack_bf_trunc(w[6], w[7])};
        short8 afrag = __builtin_bit_cast(short8, apk);

        #pragma unroll
        for (int dt = 0; dt < 4; ++dt)
            acc[dt] = __builtin_amdgcn_mfma_f32_16x16x32_bf16(afrag, bf[cb][dt], acc[dt], 0, 0, 0);
    }

    __syncthreads();  // all waves done reading smem phase-1
    #pragma unroll
    for (int dt = 0; dt < 4; ++dt)
        #pragma unroll
        for (int reg = 0; reg < 4; ++reg)
            smem[wy * 1024 + (dt * 4 + reg) * 64 + lane] = acc[dt][reg];
    __syncthreads();

    int tt = wy * 64 + lane;
    #pragma unroll
    for (int k = 0; k < 4; ++k) {
        int o = k * 256 + tt;
        float v = smem[o] + smem[1024 + o] + smem[2048 + o] + smem[3072 + o];
        v = v > 0.f ? v : expm1f(v);  // ELU
        int vv = o >> 6, l = o & 63;
        int dt = vv >> 2, reg = vv & 3;
        int i = I0 + (l >> 4) * 4 + reg;
        int d = dt * 16 + (l & 15);
        out[((size_t)(b * N_ + i)) * (H_ * D_) + h * D_ + d] = v;
    }
}

extern "C" void kernel_launch(void* const* d_in, const int* in_sizes, int n_in,
                              void* d_out, int out_size, void* d_ws, size_t ws_size,
                              hipStream_t stream) {
    const float* x   = (const float*)d_in[0];
    const int*   adj = (const int*)d_in[1];
    const float* oh  = (const float*)d_in[2];
    const float* Wq  = (const float*)d_in[3];
    const float* Wk  = (const float*)d_in[4];
    const float* W   = (const float*)d_in[5];
    const float* a   = (const float*)d_in[6];
    float* out = (float*)d_out;
    char* ws = (char*)d_ws;

    float* v1    = (float*)(ws + V1_OFF);
    float* v2    = (float*)(ws + V2_OFF);
    float* e1    = (float*)(ws + E1_OFF);
    float* e2    = (float*)(ws + E2_OFF);
    float* cin   = (float*)(ws + C_OFF);
    float* parts = (float*)(ws + PARTS_OFF);
    unsigned short* WT   = (unsigned short*)(ws + WT_OFF);
    unsigned*       bits = (unsigned*)(ws + BITS_OFF);
    unsigned short* WhT  = (unsigned short*)(ws + WHT_OFF);

    k_prep_v<<<9, 256, 0, stream>>>(Wq, Wk, a, v1, v2);
    k_prep_wt<<<256, 256, 0, stream>>>(W, WT);
    k_e12<<<B_ * N_ / 4, 256, 0, stream>>>(x, oh, v1, v2, e1, e2);
    k_wht<<<dim3(128, 4), dim3(64, 4), 0, stream>>>(x, WT, WhT);
    k_colsum<<<dim3(8, 4, 16), 256, 0, stream>>>(adj, e1, e2, parts, bits);
    k_recip<<<128, 256, 0, stream>>>(parts, cin);
    k_main<<<dim3(128, 4, 4), dim3(64, 4), 0, stream>>>(bits, e1, e2, cin, WhT, out);
}

// Round 4
// 225.335 us; speedup vs baseline: 1.1852x; 1.1722x over previous
//
#include <hip/hip_runtime.h>
#include <hip/hip_bf16.h>
#include <math.h>

#define ALPHA 0.2f
#define LOG2E 1.4426950408889634f

constexpr int B_ = 4, N_ = 2048, F_ = 256, T_ = 8, H_ = 4, D_ = 64;
constexpr int FT = F_ + T_; // 264

using short8  = __attribute__((ext_vector_type(8))) short;
using float4v = __attribute__((ext_vector_type(4))) float;
using uint4v  = __attribute__((ext_vector_type(4))) unsigned;

#if __has_builtin(__builtin_amdgcn_exp2f)
#define EXP2F(x) __builtin_amdgcn_exp2f(x)
#else
#define EXP2F(x) exp2f(x)
#endif

// ---- workspace byte offsets (all 16B aligned) ----
#define V1_OFF    0u          // 4*264 f32
#define V2_OFF    4224u       // 4*264 f32
#define E1A_OFF   8448u       // [b][h][n] float2 {E1p,E1n}   (256 KB)
#define E2A_OFF   270592u     // [b][h][n] float2 {E2p,E2n}   (256 KB)
#define PC_OFF    532736u     // [b][h][n] f32 : E2p * c      (128 KB)
#define NC_OFF    663808u     // [b][h][n] f32 : E2n * c      (128 KB)
#define PARTS_OFF 794880u     // 16 * [b][h][n] f32 partial colsums (2 MB)
#define WT_OFF    2892032u    // 256*256 bf16 : W^T [hd][f]
#define BITS_OFF  3023104u    // [b][i][64 words] adj bitmask (2 MB)
#define WHT_OFF   5120256u    // [b][hd][j] bf16 Wh^T (4 MB)
// end: 9314560 bytes

__device__ inline unsigned short f2bf_rne(float f) {
    unsigned u = __builtin_bit_cast(unsigned, f);
    u += 0x7FFFu + ((u >> 16) & 1u);
    return (unsigned short)(u >> 16);
}
__device__ inline unsigned pack_bf_rne(float f0, float f1) {
    return (unsigned)f2bf_rne(f0) | ((unsigned)f2bf_rne(f1) << 16);
}
__device__ inline unsigned pack_bf_trunc(float f0, float f1) {
    unsigned u0 = __builtin_bit_cast(unsigned, f0);
    unsigned u1 = __builtin_bit_cast(unsigned, f1);
    return (u0 >> 16) | (u1 & 0xFFFF0000u);
}
__device__ inline void gl2lds16(const void* g, void* l) {
    __builtin_amdgcn_global_load_lds(
        (const __attribute__((address_space(1))) unsigned*)g,
        (__attribute__((address_space(3))) unsigned*)l, 16, 0, 0);
}

// K1: v1[h,f] = log2e * sum_d Wq[h,f,d]*a[h,d] ; v2 from Wk with a[h,64+d]
__global__ __launch_bounds__(256) void k_prep_v(const float* __restrict__ Wq,
                                                const float* __restrict__ Wk,
                                                const float* __restrict__ a,
                                                float* __restrict__ v1,
                                                float* __restrict__ v2) {
    int tid = blockIdx.x * 256 + threadIdx.x;
    if (tid >= 2 * H_ * FT) return;
    int sel = tid / (H_ * FT);
    int r = tid - sel * (H_ * FT);
    int h = r / FT, f = r - h * FT;
    const float* W = sel ? Wk : Wq;
    const float* av = a + h * 2 * D_ + sel * D_;
    const float* wrow = W + (size_t)(h * FT + f) * D_;
    float acc = 0.f;
    for (int d = 0; d < D_; ++d) acc += wrow[d] * av[d];
    (sel ? v2 : v1)[h * FT + f] = acc * LOG2E;
}

// K1b: WT[hd][f] = bf16(W[h][f][d])
__global__ __launch_bounds__(256) void k_prep_wt(const float* __restrict__ W,
                                                 unsigned short* __restrict__ WT) {
    int tid = blockIdx.x * 256 + threadIdx.x;  // 65536
    int hd = tid >> 8, f = tid & 255;
    int h = hd >> 6, d = hd & 63;
    WT[(size_t)hd * F_ + f] = f2bf_rne(W[((size_t)h * F_ + f) * D_ + d]);
}

// K2: per-node factored exponentials. E1A={exp2(e1'),exp2(.2 e1')}, E2A likewise.
__global__ __launch_bounds__(256) void k_e12(const float* __restrict__ x,
                                             const float* __restrict__ oh,
                                             const float* __restrict__ v1,
                                             const float* __restrict__ v2,
                                             float2* __restrict__ E1A,
                                             float2* __restrict__ E2A) {
    int lane = threadIdx.x & 63;
    int w = threadIdx.x >> 6;
    int bn = blockIdx.x * 4 + w;
    int b = bn >> 11, n = bn & (N_ - 1);
    float a1h[H_] = {0.f, 0.f, 0.f, 0.f};
    float a2h[H_] = {0.f, 0.f, 0.f, 0.f};
    const float* xrow = x + (size_t)(b * N_ + n) * F_;
    for (int c = 0; c < 4; ++c) {
        int f = c * 64 + lane;
        float xv = xrow[f];
        #pragma unroll
        for (int h = 0; h < H_; ++h) {
            a1h[h] += xv * v1[h * FT + f];
            a2h[h] += xv * v2[h * FT + f];
        }
    }
    if (lane < T_) {
        float ov = oh[(size_t)(b * N_ + n) * T_ + lane];
        #pragma unroll
        for (int h = 0; h < H_; ++h) {
            a1h[h] += ov * v1[h * FT + F_ + lane];
            a2h[h] += ov * v2[h * FT + F_ + lane];
        }
    }
    #pragma unroll
    for (int off = 32; off; off >>= 1) {
        #pragma unroll
        for (int h = 0; h < H_; ++h) {
            a1h[h] += __shfl_xor(a1h[h], off, 64);
            a2h[h] += __shfl_xor(a2h[h], off, 64);
        }
    }
    if (lane == 0) {
        #pragma unroll
        for (int h = 0; h < H_; ++h) {
            float2 v1o = {EXP2F(a1h[h]), EXP2F(ALPHA * a1h[h])};
            float2 v2o = {EXP2F(a2h[h]), EXP2F(ALPHA * a2h[h])};
            E1A[(size_t)(b * H_ + h) * N_ + n] = v1o;
            E2A[(size_t)(b * H_ + h) * N_ + n] = v2o;
        }
    }
}

// K3: WhT[b][hd][j] = bf16( sum_f x[b,j,f] * W[h,f,d] )  via MFMA
__global__ __launch_bounds__(256) void k_wht(const float* __restrict__ x,
                                             const unsigned short* __restrict__ WT,
                                             unsigned short* __restrict__ WhT) {
    int lane = threadIdx.x;       // 64
    int h = threadIdx.y;          // 4
    int jt = blockIdx.x;          // 128
    int b  = blockIdx.y;          // 4
    int j0 = jt * 16;
    int m = lane & 15, quad = lane >> 4;
    float4v zero = {0.f, 0.f, 0.f, 0.f};
    float4v acc[4] = {zero, zero, zero, zero};
    #pragma unroll 2
    for (int f0 = 0; f0 < F_; f0 += 32) {
        const float* xp = x + (size_t)(b * N_ + j0 + m) * F_ + f0 + quad * 8;
        float4v xlo = *(const float4v*)xp;
        float4v xhi = *(const float4v*)(xp + 4);
        uint4v bp = {pack_bf_rne(xlo[0], xlo[1]), pack_bf_rne(xlo[2], xlo[3]),
                     pack_bf_rne(xhi[0], xhi[1]), pack_bf_rne(xhi[2], xhi[3])};
        short8 bfrag = __builtin_bit_cast(short8, bp);
        #pragma unroll
        for (int mt = 0; mt < 4; ++mt) {
            const unsigned short* ap =
                WT + (size_t)(h * 64 + mt * 16 + m) * F_ + f0 + quad * 8;
            short8 afrag = *(const short8*)ap;
            acc[mt] = __builtin_amdgcn_mfma_f32_16x16x32_bf16(afrag, bfrag, acc[mt], 0, 0, 0);
        }
    }
    #pragma unroll
    for (int mt = 0; mt < 4; ++mt) {
        #pragma unroll
        for (int reg = 0; reg < 4; ++reg) {
            int hd = h * 64 + mt * 16 + quad * 4 + reg;
            WhT[((size_t)b * 256 + hd) * N_ + j0 + m] = f2bf_rne(acc[mt][reg]);
        }
    }
}

// K4: fused — coalesced adj read (once), bitmask production, partial column sums.
// t = max(E1p*E2p, E1n*E2n)  (exp2/max identity — no transcendental per pair)
__global__ __launch_bounds__(256) void k_colsum(const int* __restrict__ adj,
                                                const float2* __restrict__ E1A,
                                                const float2* __restrict__ E2A,
                                                float* __restrict__ part_s,
                                                unsigned* __restrict__ bits) {
    int tid = threadIdx.x;
    int jt = blockIdx.x, b = blockIdx.y, ic = blockIdx.z;
    int j = jt * 256 + tid;
    int i0 = ic * 128;
    float2 e2v[H_];
    float acc[H_] = {0.f, 0.f, 0.f, 0.f};
    #pragma unroll
    for (int h = 0; h < H_; ++h) e2v[h] = E2A[(size_t)(b * H_ + h) * N_ + j];
    const float2* e1b = E1A + (size_t)(b * H_) * N_;
    const int* ap = adj + ((size_t)(b * N_ + i0)) * N_ + j;
    int lane = tid & 63;
    #pragma unroll 8
    for (int k = 0; k < 128; ++k) {
        int i = i0 + k;
        int av = ap[(size_t)k * N_];
        unsigned long long mk = __ballot(av != 0);
        if ((tid & 31) == 0)
            bits[(size_t)(b * N_ + i) * 64 + (j >> 5)] =
                ((lane & 32) == 0) ? (unsigned)mk : (unsigned)(mk >> 32);
        #pragma unroll
        for (int h = 0; h < H_; ++h) {
            float2 e1 = e1b[h * N_ + i];                 // uniform -> s_load
            float t = fmaxf(e1.x * e2v[h].x, e1.y * e2v[h].y);
            acc[h] += (av != 0) ? t : 0.f;
        }
    }
    #pragma unroll
    for (int h = 0; h < H_; ++h)
        part_s[(size_t)ic * (B_ * H_ * N_) + (size_t)(b * H_ + h) * N_ + j] = acc[h];
}

// K5: c = 1/s (or 0), folded into E2 pair -> pc, nc
__global__ __launch_bounds__(256) void k_scale(const float* __restrict__ part_s,
                                               const float2* __restrict__ E2A,
                                               float* __restrict__ pc,
                                               float* __restrict__ nc) {
    int tid = blockIdx.x * 256 + threadIdx.x;  // 32768
    float s = 0.f;
    #pragma unroll
    for (int ic = 0; ic < 16; ++ic) s += part_s[(size_t)ic * (B_ * H_ * N_) + tid];
    float c = (s > 0.f) ? 1.f / s : 0.f;
    float2 e2 = E2A[tid];
    pc[tid] = e2.x * c;
    nc[tid] = e2.y * c;
}

// K6: block = (64,4); waves are 4 i-tiles (64 i total) sharing one j-stream.
// WhT 64j x 64d chunks staged via global_load_lds (dbuf, XOR-swizzled).
// att in-register: w = bit ? max(E1p*pc, E1n*nc) : 0.  Direct store + fused ELU.
__global__ __launch_bounds__(256, 2) void k_main(const unsigned* __restrict__ bits,
                                                 const float2* __restrict__ E1A,
                                                 const float* __restrict__ pc_g,
                                                 const float* __restrict__ nc_g,
                                                 const unsigned short* __restrict__ WhT,
                                                 float* __restrict__ out) {
    __shared__ float sPC[2048];                // 8 KB
    __shared__ float sNC[2048];                // 8 KB
    __shared__ unsigned short sW[2][4096];     // 2 x 8 KB (64j x 64d bf16, swizzled)
    int lane = threadIdx.x;   // 64
    int wy = threadIdx.y;     // 4 : i-tile
    int it = blockIdx.x;      // 32
    int b  = blockIdx.y;      // 4
    int h  = blockIdx.z;      // 4
    int ibase = it * 64 + wy * 16;
    int m = lane & 15, quad = lane >> 4;
    int bh = b * H_ + h;

    // stage pc/nc (one-time)
    {
        int base = (wy * 64 + lane) * 8;
        const float* p = pc_g + (size_t)bh * N_ + base;
        const float* n = nc_g + (size_t)bh * N_ + base;
        *(float4v*)&sPC[base]     = *(const float4v*)p;
        *(float4v*)&sPC[base + 4] = *(const float4v*)(p + 4);
        *(float4v*)&sNC[base]     = *(const float4v*)n;
        *(float4v*)&sNC[base + 4] = *(const float4v*)(n + 4);
    }
    float2 e1v = E1A[(size_t)bh * N_ + ibase + m];
    const unsigned short* bbase = WhT + (size_t)(b * 256 + h * 64) * N_;
    const unsigned* brow = bits + ((size_t)(b * N_) + ibase + m) * 64;

    // stage one 64j x 64d chunk into sW[buf] (XOR-swizzled for conflict-free reads)
    auto stage = [&](int buf, int jb) {
        #pragma unroll
        for (int s2 = 0; s2 < 2; ++s2) {
            int phi = s2 * 256 + wy * 64 + lane;    // 0..511
            int r = phi >> 3, sg = phi & 7;
            int g = sg ^ (r & 7);
            const unsigned short* gp = bbase + (size_t)r * N_ + jb + g * 8;
            void* lp = (void*)&sW[buf][(s2 * 256 + wy * 64) * 8];  // wave-uniform
            gl2lds16(gp, lp);
        }
    };

    stage(0, 0);
    __syncthreads();

    float4v zero = {0.f, 0.f, 0.f, 0.f};
    float4v acc[4] = {zero, zero, zero, zero};
    uint4v bw = {0, 0, 0, 0};

    for (int k = 0; k < 32; ++k) {
        if (k < 31) stage((k + 1) & 1, (k + 1) * 64);
        if ((k & 1) == 0) bw = *(const uint4v*)(brow + k * 2);
        #pragma unroll
        for (int u = 0; u < 2; ++u) {
            int t = 2 * k + u;
            unsigned word = bw[(k & 1) * 2 + u];
            unsigned wq = word >> (quad * 8);
            int jl = t * 32 + quad * 8;
            float4v p0 = *(const float4v*)&sPC[jl];
            float4v p1 = *(const float4v*)&sPC[jl + 4];
            float4v n0 = *(const float4v*)&sNC[jl];
            float4v n1 = *(const float4v*)&sNC[jl + 4];
            float w[8];
            #pragma unroll
            for (int e = 0; e < 4; ++e) {
                float t1 = fmaxf(e1v.x * p0[e], e1v.y * n0[e]);
                w[e] = (wq & (1u << e)) ? t1 : 0.f;
            }
            #pragma unroll
            for (int e = 0; e < 4; ++e) {
                float t1 = fmaxf(e1v.x * p1[e], e1v.y * n1[e]);
                w[4 + e] = (wq & (16u << e)) ? t1 : 0.f;
            }
            uint4v apk = {pack_bf_trunc(w[0], w[1]), pack_bf_trunc(w[2], w[3]),
                          pack_bf_trunc(w[4], w[5]), pack_bf_trunc(w[6], w[7])};
            short8 afrag = __builtin_bit_cast(short8, apk);
            #pragma unroll
            for (int dt = 0; dt < 4; ++dt) {
                int r = dt * 16 + m;
                int seg = (u * 4 + quad) ^ (m & 7);
                short8 bfrag = *(const short8*)&sW[k & 1][r * 64 + seg * 8];
                acc[dt] = __builtin_amdgcn_mfma_f32_16x16x32_bf16(afrag, bfrag, acc[dt], 0, 0, 0);
            }
        }
        __syncthreads();
    }

    #pragma unroll
    for (int dt = 0; dt < 4; ++dt) {
        #pragma unroll
        for (int reg = 0; reg < 4; ++reg) {
            int i = ibase + quad * 4 + reg;
            int d = dt * 16 + m;
            float v = acc[dt][reg];
            v = v > 0.f ? v : expm1f(v);  // ELU
            out[((size_t)(b * N_ + i)) * (H_ * D_) + h * D_ + d] = v;
        }
    }
}

extern "C" void kernel_launch(void* const* d_in, const int* in_sizes, int n_in,
                              void* d_out, int out_size, void* d_ws, size_t ws_size,
                              hipStream_t stream) {
    const float* x   = (const float*)d_in[0];
    const int*   adj = (const int*)d_in[1];
    const float* oh  = (const float*)d_in[2];
    const float* Wq  = (const float*)d_in[3];
    const float* Wk  = (const float*)d_in[4];
    const float* W   = (const float*)d_in[5];
    const float* a   = (const float*)d_in[6];
    float* out = (float*)d_out;
    char* ws = (char*)d_ws;

    float*  v1    = (float*)(ws + V1_OFF);
    float*  v2    = (float*)(ws + V2_OFF);
    float2* E1A   = (float2*)(ws + E1A_OFF);
    float2* E2A   = (float2*)(ws + E2A_OFF);
    float*  pc    = (float*)(ws + PC_OFF);
    float*  nc    = (float*)(ws + NC_OFF);
    float*  parts = (float*)(ws + PARTS_OFF);
    unsigned short* WT   = (unsigned short*)(ws + WT_OFF);
    unsigned*       bits = (unsigned*)(ws + BITS_OFF);
    unsigned short* WhT  = (unsigned short*)(ws + WHT_OFF);

    k_prep_v<<<9, 256, 0, stream>>>(Wq, Wk, a, v1, v2);
    k_prep_wt<<<256, 256, 0, stream>>>(W, WT);
    k_e12<<<B_ * N_ / 4, 256, 0, stream>>>(x, oh, v1, v2, E1A, E2A);
    k_wht<<<dim3(128, 4), dim3(64, 4), 0, stream>>>(x, WT, WhT);
    k_colsum<<<dim3(8, 4, 16), 256, 0, stream>>>(adj, E1A, E2A, parts, bits);
    k_scale<<<128, 256, 0, stream>>>(parts, E2A, pc, nc);
    k_main<<<dim3(32, 4, 4), dim3(64, 4), 0, stream>>>(bits, E1A, pc, nc, WhT, out);
}

// Round 5
// 192.710 us; speedup vs baseline: 1.3858x; 1.1693x over previous
//
#include <hip/hip_runtime.h>
#include <hip/hip_bf16.h>
#include <math.h>

#define ALPHA 0.2f
#define LOG2E 1.4426950408889634f

constexpr int B_ = 4, N_ = 2048, F_ = 256, T_ = 8, H_ = 4, D_ = 64;
constexpr int FT = F_ + T_; // 264

using short8  = __attribute__((ext_vector_type(8))) short;
using float4v = __attribute__((ext_vector_type(4))) float;
using uint4v  = __attribute__((ext_vector_type(4))) unsigned;

#if __has_builtin(__builtin_amdgcn_exp2f)
#define EXP2F(x) __builtin_amdgcn_exp2f(x)
#else
#define EXP2F(x) exp2f(x)
#endif

// ---- workspace byte offsets (all 16B aligned; total 9314560 B, same as r4) ----
#define V1_OFF    0u          // 4*264 f32
#define V2_OFF    4224u       // 4*264 f32
#define E1A_OFF   8448u       // [b][h][n] float2 {E1p,E1n}   (256 KB)
#define E2A_OFF   270592u     // [b][h][n] float2 {E2p,E2n}   (256 KB)
#define PC_OFF    532736u     // [b][h][n] f32 : E2p * c      (128 KB)
#define NC_OFF    663808u     // [b][h][n] f32 : E2n * c      (128 KB)
#define PARTS_OFF 794880u     // 16 * [b][h][n] f32 partial colsums (2 MB)
#define WT_OFF    2892032u    // 256*256 bf16 : W^T [hd][f]
#define BITS_OFF  3023104u    // [b][i][64 words] adj bitmask (2 MB)
#define WHT_OFF   5120256u    // [b][hd][j] bf16 Wh^T (4 MB)

__device__ inline unsigned short f2bf_rne(float f) {
    unsigned u = __builtin_bit_cast(unsigned, f);
    u += 0x7FFFu + ((u >> 16) & 1u);
    return (unsigned short)(u >> 16);
}
__device__ inline unsigned pack_bf_rne(float f0, float f1) {
    return (unsigned)f2bf_rne(f0) | ((unsigned)f2bf_rne(f1) << 16);
}
__device__ inline unsigned pack_bf_trunc(float f0, float f1) {
    unsigned u0 = __builtin_bit_cast(unsigned, f0);
    unsigned u1 = __builtin_bit_cast(unsigned, f1);
    return (u0 >> 16) | (u1 & 0xFFFF0000u);
}
__device__ inline void gl2lds16(const void* g, void* l) {
    __builtin_amdgcn_global_load_lds(
        (const __attribute__((address_space(1))) unsigned*)g,
        (__attribute__((address_space(3))) unsigned*)l, 16, 0, 0);
}

// K0: adj (int32 0/1, 64 MB) -> bitmask (2 MB). Coalesced read, ballot pack. BW-floor.
__global__ __launch_bounds__(256) void k_adjpack(const int* __restrict__ adj,
                                                 unsigned* __restrict__ bits) {
    size_t tid = (size_t)blockIdx.x * 256 + threadIdx.x;  // 16,777,216 total
    int av = adj[tid];
    unsigned long long msk = __ballot(av != 0);
    int lane = threadIdx.x & 63;
    if (lane == 0)       bits[tid >> 5] = (unsigned)msk;
    else if (lane == 32) bits[tid >> 5] = (unsigned)(msk >> 32);
}

// K1: v1[h,f] = log2e * sum_d Wq[h,f,d]*a[h,d] ; v2 from Wk with a[h,64+d]
__global__ __launch_bounds__(256) void k_prep_v(const float* __restrict__ Wq,
                                                const float* __restrict__ Wk,
                                                const float* __restrict__ a,
                                                float* __restrict__ v1,
                                                float* __restrict__ v2) {
    int tid = blockIdx.x * 256 + threadIdx.x;
    if (tid >= 2 * H_ * FT) return;
    int sel = tid / (H_ * FT);
    int r = tid - sel * (H_ * FT);
    int h = r / FT, f = r - h * FT;
    const float* W = sel ? Wk : Wq;
    const float* av = a + h * 2 * D_ + sel * D_;
    const float* wrow = W + (size_t)(h * FT + f) * D_;
    float acc = 0.f;
    for (int d = 0; d < D_; ++d) acc += wrow[d] * av[d];
    (sel ? v2 : v1)[h * FT + f] = acc * LOG2E;
}

// K1b: WT[hd][f] = bf16(W[h][f][d])
__global__ __launch_bounds__(256) void k_prep_wt(const float* __restrict__ W,
                                                 unsigned short* __restrict__ WT) {
    int tid = blockIdx.x * 256 + threadIdx.x;  // 65536
    int hd = tid >> 8, f = tid & 255;
    int h = hd >> 6, d = hd & 63;
    WT[(size_t)hd * F_ + f] = f2bf_rne(W[((size_t)h * F_ + f) * D_ + d]);
}

// K2: per-node factored exponentials. E1A={exp2(e1'),exp2(.2 e1')}, E2A likewise.
__global__ __launch_bounds__(256) void k_e12(const float* __restrict__ x,
                                             const float* __restrict__ oh,
                                             const float* __restrict__ v1,
                                             const float* __restrict__ v2,
                                             float2* __restrict__ E1A,
                                             float2* __restrict__ E2A) {
    int lane = threadIdx.x & 63;
    int w = threadIdx.x >> 6;
    int bn = blockIdx.x * 4 + w;
    int b = bn >> 11, n = bn & (N_ - 1);
    float a1h[H_] = {0.f, 0.f, 0.f, 0.f};
    float a2h[H_] = {0.f, 0.f, 0.f, 0.f};
    const float* xrow = x + (size_t)(b * N_ + n) * F_;
    for (int c = 0; c < 4; ++c) {
        int f = c * 64 + lane;
        float xv = xrow[f];
        #pragma unroll
        for (int h = 0; h < H_; ++h) {
            a1h[h] += xv * v1[h * FT + f];
            a2h[h] += xv * v2[h * FT + f];
        }
    }
    if (lane < T_) {
        float ov = oh[(size_t)(b * N_ + n) * T_ + lane];
        #pragma unroll
        for (int h = 0; h < H_; ++h) {
            a1h[h] += ov * v1[h * FT + F_ + lane];
            a2h[h] += ov * v2[h * FT + F_ + lane];
        }
    }
    #pragma unroll
    for (int off = 32; off; off >>= 1) {
        #pragma unroll
        for (int h = 0; h < H_; ++h) {
            a1h[h] += __shfl_xor(a1h[h], off, 64);
            a2h[h] += __shfl_xor(a2h[h], off, 64);
        }
    }
    if (lane == 0) {
        #pragma unroll
        for (int h = 0; h < H_; ++h) {
            float2 v1o = {EXP2F(a1h[h]), EXP2F(ALPHA * a1h[h])};
            float2 v2o = {EXP2F(a2h[h]), EXP2F(ALPHA * a2h[h])};
            E1A[(size_t)(b * H_ + h) * N_ + n] = v1o;
            E2A[(size_t)(b * H_ + h) * N_ + n] = v2o;
        }
    }
}

// K3: WhT[b][hd][j] = bf16( sum_f x[b,j,f] * W[h,f,d] )  via MFMA
__global__ __launch_bounds__(256) void k_wht(const float* __restrict__ x,
                                             const unsigned short* __restrict__ WT,
                                             unsigned short* __restrict__ WhT) {
    int lane = threadIdx.x;       // 64
    int h = threadIdx.y;          // 4
    int jt = blockIdx.x;          // 128
    int b  = blockIdx.y;          // 4
    int j0 = jt * 16;
    int m = lane & 15, quad = lane >> 4;
    float4v zero = {0.f, 0.f, 0.f, 0.f};
    float4v acc[4] = {zero, zero, zero, zero};
    #pragma unroll 2
    for (int f0 = 0; f0 < F_; f0 += 32) {
        const float* xp = x + (size_t)(b * N_ + j0 + m) * F_ + f0 + quad * 8;
        float4v xlo = *(const float4v*)xp;
        float4v xhi = *(const float4v*)(xp + 4);
        uint4v bp = {pack_bf_rne(xlo[0], xlo[1]), pack_bf_rne(xlo[2], xlo[3]),
                     pack_bf_rne(xhi[0], xhi[1]), pack_bf_rne(xhi[2], xhi[3])};
        short8 bfrag = __builtin_bit_cast(short8, bp);
        #pragma unroll
        for (int mt = 0; mt < 4; ++mt) {
            const unsigned short* ap =
                WT + (size_t)(h * 64 + mt * 16 + m) * F_ + f0 + quad * 8;
            short8 afrag = *(const short8*)ap;
            acc[mt] = __builtin_amdgcn_mfma_f32_16x16x32_bf16(afrag, bfrag, acc[mt], 0, 0, 0);
        }
    }
    #pragma unroll
    for (int mt = 0; mt < 4; ++mt) {
        #pragma unroll
        for (int reg = 0; reg < 4; ++reg) {
            int hd = h * 64 + mt * 16 + quad * 4 + reg;
            WhT[((size_t)b * 256 + hd) * N_ + j0 + m] = f2bf_rne(acc[mt][reg]);
        }
    }
}

// K4: partial column sums from the 2 MB L2-resident bitmask (no adj re-read).
// t = max(E1p*E2p, E1n*E2n); grid (8 jt, 4 b, 16 ic), 128 rows/block.
__global__ __launch_bounds__(256) void k_colsum(const unsigned* __restrict__ bits,
                                                const float2* __restrict__ E1A,
                                                const float2* __restrict__ E2A,
                                                float* __restrict__ part_s) {
    int tid = threadIdx.x;
    int jt = blockIdx.x, b = blockIdx.y, ic = blockIdx.z;
    int j = jt * 256 + tid;
    int i0 = ic * 128;
    float2 e2v[H_];
    float acc[H_] = {0.f, 0.f, 0.f, 0.f};
    #pragma unroll
    for (int h = 0; h < H_; ++h) e2v[h] = E2A[(size_t)(b * H_ + h) * N_ + j];
    const float2* e1b = E1A + (size_t)(b * H_) * N_;
    const unsigned* bp = bits + ((size_t)(b * N_ + i0)) * 64 + (j >> 5);
    unsigned sh = j & 31;
    #pragma unroll 8
    for (int k = 0; k < 128; ++k) {
        unsigned wv = bp[(size_t)k * 64];
        bool on = (wv >> sh) & 1u;
        int i = i0 + k;
        #pragma unroll
        for (int h = 0; h < H_; ++h) {
            float2 e1 = e1b[h * N_ + i];                 // uniform -> s_load
            float t = fmaxf(e1.x * e2v[h].x, e1.y * e2v[h].y);
            acc[h] += on ? t : 0.f;
        }
    }
    #pragma unroll
    for (int h = 0; h < H_; ++h)
        part_s[(size_t)ic * (B_ * H_ * N_) + (size_t)(b * H_ + h) * N_ + j] = acc[h];
}

// K5: c = 1/s (or 0), folded into E2 pair -> pc, nc
__global__ __launch_bounds__(256) void k_scale(const float* __restrict__ part_s,
                                               const float2* __restrict__ E2A,
                                               float* __restrict__ pc,
                                               float* __restrict__ nc) {
    int tid = blockIdx.x * 256 + threadIdx.x;  // 32768
    float s = 0.f;
    #pragma unroll
    for (int ic = 0; ic < 16; ++ic) s += part_s[(size_t)ic * (B_ * H_ * N_) + tid];
    float c = (s > 0.f) ? 1.f / s : 0.f;
    float2 e2 = E2A[tid];
    pc[tid] = e2.x * c;
    nc[tid] = e2.y * c;
}

// K6: block (64,8) = 8 waves: 4 i-tiles x 2 j-half-streams over one (b,h).
// WhT chunks staged via global_load_lds (per-half double buffer, XOR-swizzled).
// Cross-half LDS reduction + fused ELU; single coalesced store.
__global__ __launch_bounds__(512, 4) void k_main(const unsigned* __restrict__ bits,
                                                 const float2* __restrict__ E1A,
                                                 const float* __restrict__ pc_g,
                                                 const float* __restrict__ nc_g,
                                                 const unsigned short* __restrict__ WhT,
                                                 float* __restrict__ out) {
    __shared__ float sPC[2048];                 // 8 KB
    __shared__ float sNC[2048];                 // 8 KB
    __shared__ unsigned short sW[2][2][4096];   // [half][buf] 32 KB; reused as sRed
    int lane = threadIdx.x;   // 64
    int wy = threadIdx.y;     // 8
    int iT = wy & 3, hf = wy >> 2;
    int it = blockIdx.x;      // 32
    int b  = blockIdx.y;      // 4
    int h  = blockIdx.z;      // 4
    int ibase = it * 64 + iT * 16;
    int m = lane & 15, quad = lane >> 4;
    int bh = b * H_ + h;

    // stage pc/nc (one-time): 512 threads x 4 floats per array
    {
        int base = (wy * 64 + lane) * 4;
        *(float4v*)&sPC[base] = *(const float4v*)(pc_g + (size_t)bh * N_ + base);
        *(float4v*)&sNC[base] = *(const float4v*)(nc_g + (size_t)bh * N_ + base);
    }
    float2 e1v = E1A[(size_t)bh * N_ + ibase + m];
    const unsigned short* bbase = WhT + (size_t)(b * 256 + h * 64) * N_;
    const unsigned* brow = bits + ((size_t)(b * N_) + ibase + m) * 64 + hf * 32;

    // stage one 64j x 64d chunk of this wave's half into sW[hf][buf]
    auto stage = [&](int buf, int jb) {
        #pragma unroll
        for (int s2 = 0; s2 < 2; ++s2) {
            int phi = s2 * 256 + iT * 64 + lane;    // 0..511
            int r = phi >> 3, sg = phi & 7;
            int g = sg ^ (r & 7);
            const unsigned short* gp = bbase + (size_t)r * N_ + hf * 1024 + jb + g * 8;
            void* lp = (void*)&sW[hf][buf][(s2 * 256 + iT * 64) * 8];  // wave-uniform
            gl2lds16(gp, lp);
        }
    };

    stage(0, 0);
    __syncthreads();

    float4v zero = {0.f, 0.f, 0.f, 0.f};
    float4v acc[4] = {zero, zero, zero, zero};
    uint4v bw = {0, 0, 0, 0};

    for (int k = 0; k < 16; ++k) {
        if (k < 15) stage((k + 1) & 1, (k + 1) * 64);
        if ((k & 1) == 0) bw = *(const uint4v*)(brow + k * 2);
        #pragma unroll
        for (int u = 0; u < 2; ++u) {
            int t = 2 * k + u;
            unsigned word = bw[(k & 1) * 2 + u];
            unsigned wq = word >> (quad * 8);
            int jl = hf * 1024 + t * 32 + quad * 8;
            float4v p0 = *(const float4v*)&sPC[jl];
            float4v p1 = *(const float4v*)&sPC[jl + 4];
            float4v n0 = *(const float4v*)&sNC[jl];
            float4v n1 = *(const float4v*)&sNC[jl + 4];
            float w[8];
            #pragma unroll
            for (int e = 0; e < 4; ++e) {
                float t1 = fmaxf(e1v.x * p0[e], e1v.y * n0[e]);
                w[e] = (wq & (1u << e)) ? t1 : 0.f;
            }
            #pragma unroll
            for (int e = 0; e < 4; ++e) {
                float t1 = fmaxf(e1v.x * p1[e], e1v.y * n1[e]);
                w[4 + e] = (wq & (16u << e)) ? t1 : 0.f;
            }
            uint4v apk = {pack_bf_trunc(w[0], w[1]), pack_bf_trunc(w[2], w[3]),
                          pack_bf_trunc(w[4], w[5]), pack_bf_trunc(w[6], w[7])};
            short8 afrag = __builtin_bit_cast(short8, apk);
            #pragma unroll
            for (int dt = 0; dt < 4; ++dt) {
                int r = dt * 16 + m;
                int seg = (u * 4 + quad) ^ (m & 7);
                short8 bfrag = *(const short8*)&sW[hf][k & 1][r * 64 + seg * 8];
                acc[dt] = __builtin_amdgcn_mfma_f32_16x16x32_bf16(afrag, bfrag, acc[dt], 0, 0, 0);
            }
        }
        __syncthreads();
    }

    // cross-half reduction (reuse sW region as float scratch)
    float* sRed = (float*)&sW[0][0][0];  // 8192 floats
    #pragma unroll
    for (int dt = 0; dt < 4; ++dt)
        #pragma unroll
        for (int reg = 0; reg < 4; ++reg)
            sRed[wy * 1024 + (dt * 4 + reg) * 64 + lane] = acc[dt][reg];
    __syncthreads();

    int tt = wy * 64 + lane;  // 0..511
    #pragma unroll
    for (int s = 0; s < 8; ++s) {
        int v = s * 512 + tt;                    // 0..4095
        float val = sRed[v] + sRed[4096 + v];
        val = val > 0.f ? val : expm1f(val);     // ELU
        int iT2 = v >> 10, rr = (v >> 6) & 15, l = v & 63;
        int dt = rr >> 2, reg = rr & 3;
        int i = it * 64 + iT2 * 16 + (l >> 4) * 4 + reg;
        int d = dt * 16 + (l & 15);
        out[((size_t)(b * N_ + i)) * (H_ * D_) + h * D_ + d] = val;
    }
}

extern "C" void kernel_launch(void* const* d_in, const int* in_sizes, int n_in,
                              void* d_out, int out_size, void* d_ws, size_t ws_size,
                              hipStream_t stream) {
    const float* x   = (const float*)d_in[0];
    const int*   adj = (const int*)d_in[1];
    const float* oh  = (const float*)d_in[2];
    const float* Wq  = (const float*)d_in[3];
    const float* Wk  = (const float*)d_in[4];
    const float* W   = (const float*)d_in[5];
    const float* a   = (const float*)d_in[6];
    float* out = (float*)d_out;
    char* ws = (char*)d_ws;

    float*  v1    = (float*)(ws + V1_OFF);
    float*  v2    = (float*)(ws + V2_OFF);
    float2* E1A   = (float2*)(ws + E1A_OFF);
    float2* E2A   = (float2*)(ws + E2A_OFF);
    float*  pc    = (float*)(ws + PC_OFF);
    float*  nc    = (float*)(ws + NC_OFF);
    float*  parts = (float*)(ws + PARTS_OFF);
    unsigned short* WT   = (unsigned short*)(ws + WT_OFF);
    unsigned*       bits = (unsigned*)(ws + BITS_OFF);
    unsigned short* WhT  = (unsigned short*)(ws + WHT_OFF);

    k_adjpack<<<65536, 256, 0, stream>>>(adj, bits);
    k_prep_v<<<9, 256, 0, stream>>>(Wq, Wk, a, v1, v2);
    k_prep_wt<<<256, 256, 0, stream>>>(W, WT);
    k_e12<<<B_ * N_ / 4, 256, 0, stream>>>(x, oh, v1, v2, E1A, E2A);
    k_wht<<<dim3(128, 4), dim3(64, 4), 0, stream>>>(x, WT, WhT);
    k_colsum<<<dim3(8, 4, 16), 256, 0, stream>>>(bits, E1A, E2A, parts);
    k_scale<<<128, 256, 0, stream>>>(parts, E2A, pc, nc);
    k_main<<<dim3(32, 4, 4), dim3(64, 8), 0, stream>>>(bits, E1A, pc, nc, WhT, out);
}

// Round 8
// 185.519 us; speedup vs baseline: 1.4395x; 1.0388x over previous
//
#include <hip/hip_runtime.h>
#include <hip/hip_bf16.h>
#include <math.h>

#define ALPHA 0.2f
#define LOG2E 1.4426950408889634f

constexpr int B_ = 4, N_ = 2048, F_ = 256, T_ = 8, H_ = 4, D_ = 64;
constexpr int FT = F_ + T_; // 264

using half8   = __attribute__((ext_vector_type(8))) _Float16;
using half2v  = __attribute__((ext_vector_type(2))) _Float16;
using float4v = __attribute__((ext_vector_type(4))) float;
using uint4v  = __attribute__((ext_vector_type(4))) unsigned;

#if __has_builtin(__builtin_amdgcn_exp2f)
#define EXP2F(x) __builtin_amdgcn_exp2f(x)
#else
#define EXP2F(x) exp2f(x)
#endif

__device__ inline unsigned pkrtz_u(float a, float b) {
    return __builtin_bit_cast(unsigned, __builtin_amdgcn_cvt_pkrtz(a, b));
}

// ---- workspace byte offsets (16B aligned; total 9314560 B == r4/r5 passing footprint) ----
#define V1_OFF    0u          // 4*264 f32
#define V2_OFF    4224u       // 4*264 f32
#define E1A_OFF   8448u       // [b][h][n] float2 {P1,N1} fp32        (256 KB)
#define E2A_OFF   270592u     // [b][h][n] float2 {P2,N2} fp32        (256 KB)
#define PC_OFF    532736u     // [b][h][n] f32 : pc = P2/s            (128 KB)
#define NC_OFF    663808u     // [b][h][n] f32 : nc = N2/s            (128 KB)
#define PARTS_OFF 794880u     // 16 x [b][h][n] f32 partial colsums   (2 MB)
#define WT_OFF    2892032u    // 256*256 fp16 : W^T [hd][f]           (128 KB)
#define BITS_OFF  3023104u    // [b][i][64 words] adj bitmask         (2 MB)
#define WHT_OFF   5120256u    // [b][hd][j] fp16 Wh^T                 (4 MB)
// end: 9314560

__device__ inline void gl2lds16(const void* g, void* l) {
    __builtin_amdgcn_global_load_lds(
        (const __attribute__((address_space(1))) unsigned*)g,
        (__attribute__((address_space(3))) unsigned*)l, 16, 0, 0);
}

// K0: adj (int32 0/1, 64 MB) -> bitmask (2 MB). Coalesced, ballot pack. HBM-floor.
__global__ __launch_bounds__(256) void k_adjpack(const int* __restrict__ adj,
                                                 unsigned* __restrict__ bits) {
    size_t tid = (size_t)blockIdx.x * 256 + threadIdx.x;
    int av = adj[tid];
    unsigned long long msk = __ballot(av != 0);
    int lane = threadIdx.x & 63;
    if (lane == 0)       bits[tid >> 5] = (unsigned)msk;
    else if (lane == 32) bits[tid >> 5] = (unsigned)(msk >> 32);
}

// K1 (merged): blocks 0..255 -> WT fp16; block 256+ -> v1/v2.
__global__ __launch_bounds__(256) void k_prep(const float* __restrict__ Wq,
                                              const float* __restrict__ Wk,
                                              const float* __restrict__ a,
                                              const float* __restrict__ W,
                                              float* __restrict__ v1,
                                              float* __restrict__ v2,
                                              _Float16* __restrict__ WT) {
    int gid = blockIdx.x * 256 + threadIdx.x;
    if (gid < 65536) {
        int hd = gid >> 8, f = gid & 255;
        int h = hd >> 6, d = hd & 63;
        WT[(size_t)hd * F_ + f] = (_Float16)W[((size_t)h * F_ + f) * D_ + d];
        return;
    }
    int tid = gid - 65536;
    if (tid >= 2 * H_ * FT) return;
    int sel = tid / (H_ * FT);
    int r = tid - sel * (H_ * FT);
    int h = r / FT, f = r - h * FT;
    const float* Wx = sel ? Wk : Wq;
    const float* av = a + h * 2 * D_ + sel * D_;
    const float* wrow = Wx + (size_t)(h * FT + f) * D_;
    float acc = 0.f;
    for (int d = 0; d < D_; ++d) acc += wrow[d] * av[d];
    (sel ? v2 : v1)[h * FT + f] = acc * LOG2E;
}

// K2: per-node factored exponentials (fp32)
__global__ __launch_bounds__(256) void k_e12(const float* __restrict__ x,
                                             const float* __restrict__ oh,
                                             const float* __restrict__ v1,
                                             const float* __restrict__ v2,
                                             float2* __restrict__ E1A,
                                             float2* __restrict__ E2A) {
    int lane = threadIdx.x & 63;
    int w = threadIdx.x >> 6;
    int bn = blockIdx.x * 4 + w;
    int b = bn >> 11, n = bn & (N_ - 1);
    float a1h[H_] = {0.f, 0.f, 0.f, 0.f};
    float a2h[H_] = {0.f, 0.f, 0.f, 0.f};
    const float* xrow = x + (size_t)(b * N_ + n) * F_;
    for (int c = 0; c < 4; ++c) {
        int f = c * 64 + lane;
        float xv = xrow[f];
        #pragma unroll
        for (int h = 0; h < H_; ++h) {
            a1h[h] += xv * v1[h * FT + f];
            a2h[h] += xv * v2[h * FT + f];
        }
    }
    if (lane < T_) {
        float ov = oh[(size_t)(b * N_ + n) * T_ + lane];
        #pragma unroll
        for (int h = 0; h < H_; ++h) {
            a1h[h] += ov * v1[h * FT + F_ + lane];
            a2h[h] += ov * v2[h * FT + F_ + lane];
        }
    }
    #pragma unroll
    for (int off = 32; off; off >>= 1) {
        #pragma unroll
        for (int h = 0; h < H_; ++h) {
            a1h[h] += __shfl_xor(a1h[h], off, 64);
            a2h[h] += __shfl_xor(a2h[h], off, 64);
        }
    }
    if (lane == 0) {
        #pragma unroll
        for (int h = 0; h < H_; ++h) {
            size_t o = (size_t)(b * H_ + h) * N_ + n;
            E1A[o] = {EXP2F(a1h[h]), EXP2F(ALPHA * a1h[h])};
            E2A[o] = {EXP2F(a2h[h]), EXP2F(ALPHA * a2h[h])};
        }
    }
}

// K3: WhT[b][hd][j] = fp16( sum_f x[b,j,f] * W[h,f,d] )  via fp16 MFMA
__global__ __launch_bounds__(256) void k_wht(const float* __restrict__ x,
                                             const _Float16* __restrict__ WT,
                                             _Float16* __restrict__ WhT) {
    int lane = threadIdx.x;       // 64
    int h = threadIdx.y;          // 4
    int jt = blockIdx.x;          // 128
    int b  = blockIdx.y;          // 4
    int j0 = jt * 16;
    int m = lane & 15, quad = lane >> 4;
    float4v zero = {0.f, 0.f, 0.f, 0.f};
    float4v acc[4] = {zero, zero, zero, zero};
    #pragma unroll 2
    for (int f0 = 0; f0 < F_; f0 += 32) {
        const float* xp = x + (size_t)(b * N_ + j0 + m) * F_ + f0 + quad * 8;
        float4v xlo = *(const float4v*)xp;
        float4v xhi = *(const float4v*)(xp + 4);
        uint4v bp = {pkrtz_u(xlo[0], xlo[1]), pkrtz_u(xlo[2], xlo[3]),
                     pkrtz_u(xhi[0], xhi[1]), pkrtz_u(xhi[2], xhi[3])};
        half8 bfrag = __builtin_bit_cast(half8, bp);
        #pragma unroll
        for (int mt = 0; mt < 4; ++mt) {
            const _Float16* ap = WT + (size_t)(h * 64 + mt * 16 + m) * F_ + f0 + quad * 8;
            half8 afrag = *(const half8*)ap;
            acc[mt] = __builtin_amdgcn_mfma_f32_16x16x32_f16(afrag, bfrag, acc[mt], 0, 0, 0);
        }
    }
    #pragma unroll
    for (int mt = 0; mt < 4; ++mt) {
        #pragma unroll
        for (int reg = 0; reg < 4; ++reg) {
            int hd = h * 64 + mt * 16 + quad * 4 + reg;
            WhT[((size_t)b * 256 + hd) * N_ + j0 + m] = (_Float16)acc[mt][reg];
        }
    }
}

// K4: partial column sums from the L2-resident bitmask. grid (8 jt, 4 b, 16 ic).
__global__ __launch_bounds__(256) void k_colsum(const unsigned* __restrict__ bits,
                                                const float2* __restrict__ E1A,
                                                const float2* __restrict__ E2A,
                                                float* __restrict__ part_s) {
    int tid = threadIdx.x;
    int jt = blockIdx.x, b = blockIdx.y, ic = blockIdx.z;
    int j = jt * 256 + tid;
    int i0 = ic * 128;
    float2 e2v[H_];
    float acc[H_] = {0.f, 0.f, 0.f, 0.f};
    #pragma unroll
    for (int h = 0; h < H_; ++h) e2v[h] = E2A[(size_t)(b * H_ + h) * N_ + j];
    const float2* e1b = E1A + (size_t)(b * H_) * N_;
    const unsigned* bp = bits + ((size_t)(b * N_ + i0)) * 64 + (j >> 5);
    unsigned sh = j & 31;
    #pragma unroll 8
    for (int k = 0; k < 128; ++k) {
        unsigned wv = bp[(size_t)k * 64];
        bool on = (wv >> sh) & 1u;
        int i = i0 + k;
        #pragma unroll
        for (int h = 0; h < H_; ++h) {
            float2 e1 = e1b[h * N_ + i];                 // uniform -> s_load
            float t = fmaxf(e1.x * e2v[h].x, e1.y * e2v[h].y);
            acc[h] += on ? t : 0.f;
        }
    }
    #pragma unroll
    for (int h = 0; h < H_; ++h)
        part_s[(size_t)ic * (B_ * H_ * N_) + (size_t)(b * H_ + h) * N_ + j] = acc[h];
}

// K5: c = 1/s (or 0) folded into E2 -> fp32 pc, nc
__global__ __launch_bounds__(256) void k_scale(const float* __restrict__ part_s,
                                               const float2* __restrict__ E2A,
                                               float* __restrict__ pc,
                                               float* __restrict__ nc) {
    int tid = blockIdx.x * 256 + threadIdx.x;  // 32768
    float s = 0.f;
    #pragma unroll
    for (int ic = 0; ic < 16; ++ic) s += part_s[(size_t)ic * (B_ * H_ * N_) + tid];
    float c = (s > 0.f) ? 1.f / s : 0.f;
    float2 e2 = E2A[tid];
    pc[tid] = e2.x * c;
    nc[tid] = e2.y * c;
}

// K6: block (64,4): waves = 4 i-tiles (64 i) over one (b,h); j-chunks of 128.
// fp32 weight math (w = max(P1*pc, N1*nc)), pkrtz pack, LUT mask; fp16 MFMA;
// WhT staged via global_load_lds (double-buffered, 16-seg XOR swizzle).
__global__ __launch_bounds__(256, 2) void k_main(const unsigned* __restrict__ bits,
                                                 const float2* __restrict__ E1A,
                                                 const float* __restrict__ pc_g,
                                                 const float* __restrict__ nc_g,
                                                 const _Float16* __restrict__ WhT,
                                                 float* __restrict__ out) {
    __shared__ float sPC[2048];           // 8 KB
    __shared__ float sNC[2048];           // 8 KB
    __shared__ unsigned sLUT[256][4];     // 4 KB : byte -> 4 packed half-masks
    __shared__ _Float16 sW[2][8192];      // 2 x 16 KB : 64 d-rows x 128 j (swizzled)
    int lane = threadIdx.x;   // 64
    int wy = threadIdx.y;     // 4 : i-tile
    int it = blockIdx.x;      // 32
    int b  = blockIdx.y;      // 4
    int h  = blockIdx.z;      // 4
    int ibase = it * 64 + wy * 16;
    int m = lane & 15, quad = lane >> 4;
    int bh = b * H_ + h;
    int t256 = wy * 64 + lane;

    // LUT + pc/nc staging
    {
        unsigned t = t256;
        sLUT[t][0] = ((t & 1u) ? 0xFFFFu : 0u) | ((t & 2u) ? 0xFFFF0000u : 0u);
        sLUT[t][1] = ((t & 4u) ? 0xFFFFu : 0u) | ((t & 8u) ? 0xFFFF0000u : 0u);
        sLUT[t][2] = ((t & 16u) ? 0xFFFFu : 0u) | ((t & 32u) ? 0xFFFF0000u : 0u);
        sLUT[t][3] = ((t & 64u) ? 0xFFFFu : 0u) | ((t & 128u) ? 0xFFFF0000u : 0u);
        int base = t256 * 8;
        *(float4v*)&sPC[base]     = *(const float4v*)(pc_g + (size_t)bh * N_ + base);
        *(float4v*)&sPC[base + 4] = *(const float4v*)(pc_g + (size_t)bh * N_ + base + 4);
        *(float4v*)&sNC[base]     = *(const float4v*)(nc_g + (size_t)bh * N_ + base);
        *(float4v*)&sNC[base + 4] = *(const float4v*)(nc_g + (size_t)bh * N_ + base + 4);
    }
    float2 e1v = E1A[(size_t)bh * N_ + ibase + m];   // {P1, N1} for row i=ibase+m
    const _Float16* bbase = WhT + (size_t)(b * 256 + h * 64) * N_;
    const unsigned* brow = bits + ((size_t)(b * N_) + ibase + m) * 64;

    // stage a 64d x 128j chunk into sW[buf] (16-seg XOR swizzle)
    auto stage = [&](int buf, int jb) {
        #pragma unroll
        for (int q = 0; q < 4; ++q) {
            int r = q * 16 + wy * 4 + (lane >> 4);
            int g = (lane & 15) ^ (r & 15);
            const _Float16* gp = bbase + (size_t)r * N_ + jb + g * 8;
            void* lp = (void*)&sW[buf][q * 2048 + wy * 512];  // wave-uniform base
            gl2lds16(gp, lp);
        }
    };

    stage(0, 0);
    __syncthreads();

    float4v zero = {0.f, 0.f, 0.f, 0.f};
    float4v acc[4] = {zero, zero, zero, zero};

    for (int k = 0; k < 16; ++k) {
        if (k < 15) stage((k + 1) & 1, (k + 1) * 128);
        uint4v bwv = *(const uint4v*)(brow + k * 4);
        #pragma unroll
        for (int u = 0; u < 4; ++u) {
            unsigned byte = (bwv[u] >> (quad * 8)) & 0xFFu;
            uint4v msk = *(const uint4v*)&sLUT[byte][0];
            int jg = k * 128 + u * 32 + quad * 8;
            float4v p0 = *(const float4v*)&sPC[jg];
            float4v p1 = *(const float4v*)&sPC[jg + 4];
            float4v n0 = *(const float4v*)&sNC[jg];
            float4v n1 = *(const float4v*)&sNC[jg + 4];
            float w[8];
            #pragma unroll
            for (int e = 0; e < 4; ++e) w[e]     = fmaxf(e1v.x * p0[e], e1v.y * n0[e]);
            #pragma unroll
            for (int e = 0; e < 4; ++e) w[4 + e] = fmaxf(e1v.x * p1[e], e1v.y * n1[e]);
            uint4v wvp = {pkrtz_u(w[0], w[1]) & msk[0], pkrtz_u(w[2], w[3]) & msk[1],
                          pkrtz_u(w[4], w[5]) & msk[2], pkrtz_u(w[6], w[7]) & msk[3]};
            half8 afrag = __builtin_bit_cast(half8, wvp);
            #pragma unroll
            for (int dt = 0; dt < 4; ++dt) {
                int r = dt * 16 + m;
                int segp = (u * 4 + quad) ^ m;       // r & 15 == m
                half8 bfrag = *(const half8*)&sW[k & 1][r * 128 + segp * 8];
                acc[dt] = __builtin_amdgcn_mfma_f32_16x16x32_f16(afrag, bfrag, acc[dt], 0, 0, 0);
            }
        }
        __syncthreads();
    }

    #pragma unroll
    for (int dt = 0; dt < 4; ++dt) {
        #pragma unroll
        for (int reg = 0; reg < 4; ++reg) {
            int i = ibase + quad * 4 + reg;
            int d = dt * 16 + m;
            float v = acc[dt][reg];
            v = v > 0.f ? v : expm1f(v);  // ELU
            out[((size_t)(b * N_ + i)) * (H_ * D_) + h * D_ + d] = v;
        }
    }
}

extern "C" void kernel_launch(void* const* d_in, const int* in_sizes, int n_in,
                              void* d_out, int out_size, void* d_ws, size_t ws_size,
                              hipStream_t stream) {
    const float* x   = (const float*)d_in[0];
    const int*   adj = (const int*)d_in[1];
    const float* oh  = (const float*)d_in[2];
    const float* Wq  = (const float*)d_in[3];
    const float* Wk  = (const float*)d_in[4];
    const float* W   = (const float*)d_in[5];
    const float* a   = (const float*)d_in[6];
    float* out = (float*)d_out;
    char* ws = (char*)d_ws;

    float*   v1    = (float*)(ws + V1_OFF);
    float*   v2    = (float*)(ws + V2_OFF);
    float2*  E1A   = (float2*)(ws + E1A_OFF);
    float2*  E2A   = (float2*)(ws + E2A_OFF);
    float*   pc    = (float*)(ws + PC_OFF);
    float*   nc    = (float*)(ws + NC_OFF);
    float*   parts = (float*)(ws + PARTS_OFF);
    _Float16* WT   = (_Float16*)(ws + WT_OFF);
    unsigned* bits = (unsigned*)(ws + BITS_OFF);
    _Float16* WhT  = (_Float16*)(ws + WHT_OFF);

    k_adjpack<<<65536, 256, 0, stream>>>(adj, bits);
    k_prep<<<265, 256, 0, stream>>>(Wq, Wk, a, W, v1, v2, WT);
    k_e12<<<B_ * N_ / 4, 256, 0, stream>>>(x, oh, v1, v2, E1A, E2A);
    k_wht<<<dim3(128, 4), dim3(64, 4), 0, stream>>>(x, WT, WhT);
    k_colsum<<<dim3(8, 4, 16), 256, 0, stream>>>(bits, E1A, E2A, parts);
    k_scale<<<128, 256, 0, stream>>>(parts, E2A, pc, nc);
    k_main<<<dim3(32, 4, 4), dim3(64, 4), 0, stream>>>(bits, E1A, pc, nc, WhT, out);
}